// Round 16
// baseline (322.889 us; speedup 1.0000x reference)
//
#include <hip/hip_runtime.h>
#include <stdint.h>

#define EPS 1e-5f

typedef short bh8 __attribute__((ext_vector_type(8)));   // 8 bf16 in 4 VGPRs
typedef float f4v __attribute__((ext_vector_type(4)));   // MFMA accumulator
typedef unsigned short ushort_t;

static __device__ __forceinline__ unsigned short f2bf(float f) {
    unsigned u = __builtin_bit_cast(unsigned, f);
    u += 0x7fffu + ((u >> 16) & 1u);          // RNE
    return (unsigned short)(u >> 16);
}

static __device__ __forceinline__ float bfbits(unsigned x) {
    return __builtin_bit_cast(float, x);
}

// accumulate 16 bf16 channels (2×uint4) into tv
static __device__ __forceinline__ void acc16(float* tv, uint4 qa, uint4 qb) {
    unsigned wd[8] = {qa.x, qa.y, qa.z, qa.w, qb.x, qb.y, qb.z, qb.w};
#pragma unroll
    for (int p = 0; p < 8; ++p) {
        tv[2 * p + 0] += bfbits(wd[p] << 16);
        tv[2 * p + 1] += bfbits(wd[p] & 0xffff0000u);
    }
}

// ---------------- ws layout (bytes) ----------------
// Pb   (bf16): 0          size 5,120,000
// W1b  (bf16): 5,160,960  size 32,768
// Wfb  (bf16): 5,193,728  size 65,536
// W0b  (bf16): 5,259,264  size 2,048
// cnt  (int) : 5,261,312  size 2,000,000   (zeroed by prep; fill_csr restores to 0)
// rp   (int) : 9,259,264  size 2,000,004
// partials   : 11,259,392 size 492
// col  (int) : 11,261,440 size 2,000,000
// catB (bf16): 16,777,216 size 128,000,000

// prep: bf16-convert W1/Wf/W0, zero cnt
__global__ __launch_bounds__(256) void prep(const float* __restrict__ W1,
                                            const float* __restrict__ Wf,
                                            const float* __restrict__ W0,
                                            ushort_t* __restrict__ W1b,
                                            ushort_t* __restrict__ Wfb,
                                            ushort_t* __restrict__ W0b,
                                            int* __restrict__ cnt, int n) {
    int i = blockIdx.x * 256 + threadIdx.x;
    if (i < 16384) W1b[i] = f2bf(W1[i]);
    else if (i < 49152) { int j = i - 16384; Wfb[j] = f2bf(Wf[j]); }
    else if (i < 50176) { int j = i - 49152; W0b[j] = f2bf(W0[j]); }
    for (int k = i; k < n; k += gridDim.x * 256) cnt[k] = 0;
}

// ---------------- merged: P = agt_x @ Wa^T  (blocks < nbProj)  +  hist_v (rest) ----------
__global__ __launch_bounds__(256) void proj_hist(const float* __restrict__ agt,
                                                 const float* __restrict__ Wa,
                                                 unsigned short* __restrict__ Pb,
                                                 const int* __restrict__ v,
                                                 int* __restrict__ cnt,
                                                 int E, int nbProj) {
    __shared__ float WT[80 * 128];   // WT[k*128+c] = Wa[c*80+k]
    __shared__ float xT[80][32];
    int t = threadIdx.x;
    if ((int)blockIdx.x >= nbProj) {   // histogram branch (no LDS use)
        int e = ((int)blockIdx.x - nbProj) * 256 + t;
        if (e < E) atomicAdd(&cnt[v[e]], 1);
        return;
    }
    int row0 = blockIdx.x * 32;
#pragma unroll
    for (int m = 0; m < 40; ++m) {
        int f = t + 256 * m;
        int k = f >> 7, c = f & 127;
        WT[f] = Wa[c * 80 + k];
    }
#pragma unroll
    for (int m = 0; m < 10; ++m) {
        int f = t + 256 * m;
        int r = f / 80, k = f - r * 80;
        xT[k][r] = agt[(size_t)(row0 + r) * 80 + k];
    }
    __syncthreads();
    int tx = t & 31, ty = t >> 5;
    float acc[4][4] = {};
    for (int k = 0; k < 80; ++k) {
        float4 xv = *(const float4*)&xT[k][ty * 4];
        float4 wv = *(const float4*)&WT[k * 128 + tx * 4];
        float xa[4] = {xv.x, xv.y, xv.z, xv.w};
        float wa[4] = {wv.x, wv.y, wv.z, wv.w};
#pragma unroll
        for (int i = 0; i < 4; ++i)
#pragma unroll
            for (int j = 0; j < 4; ++j) acc[i][j] = fmaf(xa[i], wa[j], acc[i][j]);
    }
#pragma unroll
    for (int i = 0; i < 4; ++i) {
        int r = row0 + ty * 4 + i;
        union { unsigned short s[4]; uint2 q; } o;
#pragma unroll
        for (int j = 0; j < 4; ++j) o.s[j] = f2bf(acc[i][j]);
        *(uint2*)&Pb[(size_t)r * 128 + tx * 4] = o.q;
    }
}

__global__ __launch_bounds__(256) void scan1(const int* __restrict__ cnt,
                                             int* __restrict__ rp,
                                             int* __restrict__ partials, int n) {
    __shared__ int lds[256];
    int b = blockIdx.x, t = threadIdx.x;
    int base = b * 4096 + t * 16;
    int vv[16];
    int run = 0;
#pragma unroll
    for (int i = 0; i < 16; ++i) {
        int c = (base + i < n) ? cnt[base + i] : 0;
        vv[i] = run;
        run += c;
    }
    lds[t] = run;
    __syncthreads();
#pragma unroll
    for (int off = 1; off < 256; off <<= 1) {
        int x = (t >= off) ? lds[t - off] : 0;
        __syncthreads();
        lds[t] += x;
        __syncthreads();
    }
    int excl = lds[t] - run;
    if (t == 255) partials[b] = lds[255];
#pragma unroll
    for (int i = 0; i < 16; ++i)
        if (base + i < n) rp[base + i] = excl + vv[i];
}

// scan3 with scan2 folded in
__global__ __launch_bounds__(256) void scan3(int* __restrict__ rp,
                                             const int* __restrict__ partials,
                                             int n, int E, int nb) {
    __shared__ int pref;
    int i = blockIdx.x * 256 + threadIdx.x;
    int chunk = (blockIdx.x * 256) >> 12;
    if (threadIdx.x == 0) {
        int s = 0;
        for (int b = 0; b < chunk; ++b) s += partials[b];
        pref = s;
    }
    __syncthreads();
    if (i < n) rp[i] += pref;
    if (i == 0) rp[n] = E;
}

// slot allocation via atomicSub on cnt (leaves cnt at 0 afterwards)
__global__ void fill_csr(const int* __restrict__ u, const int* __restrict__ v,
                         const int* __restrict__ rp, int* __restrict__ cnt,
                         int* __restrict__ col, int E) {
    int e = blockIdx.x * 256 + threadIdx.x;
    if (e < E) {
        int vv = v[e];
        int pos = rp[vv] + (atomicSub(&cnt[vv], 1) - 1);
        col[pos] = u[e];
    }
}

// ---------------- gather + GN_bn + ReLU + bf16 pack -> catB[N][128] ----------------
__global__ __launch_bounds__(256) void gather_gn(
    const unsigned short* __restrict__ Pb, const int* __restrict__ rp,
    const int* __restrict__ col, const float* __restrict__ g_bn,
    const float* __restrict__ b_bn, ushort_t* __restrict__ catB) {
    const int t = threadIdx.x;
    const int node = blockIdx.x * 32 + (t >> 3);
    const int c0 = (t & 7) * 16;
    const int beg = rp[node];
    const int deg = rp[node + 1] - beg;
    const int ca = col[(deg > 0) ? beg : 0];
    const int cb = col[(deg > 1) ? beg + 1 : 0];
    const int cc = col[(deg > 2) ? beg + 2 : 0];
    const int cd = col[(deg > 3) ? beg + 3 : 0];
    const unsigned short* pB = Pb + c0;
    float tv[16] = {};
    if (deg > 0) { const uint4* p = (const uint4*)(pB + (size_t)ca * 128); acc16(tv, p[0], p[1]); }
    if (deg > 1) { const uint4* p = (const uint4*)(pB + (size_t)cb * 128); acc16(tv, p[0], p[1]); }
    if (deg > 2) { const uint4* p = (const uint4*)(pB + (size_t)cc * 128); acc16(tv, p[0], p[1]); }
    if (deg > 3) { const uint4* p = (const uint4*)(pB + (size_t)cd * 128); acc16(tv, p[0], p[1]); }
    for (int k = 4; k < deg; ++k) {
        const uint4* p = (const uint4*)(pB + (size_t)col[beg + k] * 128);
        acc16(tv, p[0], p[1]);
    }
    float a = 0.f, q = 0.f;
#pragma unroll
    for (int i = 0; i < 16; ++i) { a += tv[i]; q += tv[i] * tv[i]; }
#pragma unroll
    for (int msk = 1; msk < 8; msk <<= 1) {
        a += __shfl_xor(a, msk, 64);
        q += __shfl_xor(q, msk, 64);
    }
    const float mean = a * (1.f / 128.f);
    const float var = q * (1.f / 128.f) - mean * mean;
    const float inv = rsqrtf(var + EPS);
    union { unsigned short s[16]; uint4 q4[2]; } o;
#pragma unroll
    for (int i = 0; i < 16; ++i) {
        const int cch = c0 + i;
        o.s[i] = f2bf(fmaxf((tv[i] - mean) * inv * g_bn[cch] + b_bn[cch], 0.f));
    }
    uint4* dst = (uint4*)(catB + (size_t)node * 128 + c0);
    dst[0] = o.q4[0];
    dst[1] = o.q4[1];
}

// ---------------- fused kernel: r15 structure + s_setprio around MFMA clusters -----------
// 512 threads, 8 waves; wave w owns output cols [16w,16w+16) for BOTH tiles A/B.
// GEMM1 (K=8) zero-padded to K=32 MFMA. h0sX reused for normalized-h. 4 barriers/pair.
// setprio(1) during GEMM2/GEMM3: 3 blocks/CU run phase-skewed, so the MFMA-phase
// block preempts staging-phase blocks (cross-block diversity, m191 mechanism).
__global__ __launch_bounds__(512, 4) void fused(
    const float* __restrict__ mapx, const ushort_t* __restrict__ W0b,
    const float* __restrict__ b0, const ushort_t* __restrict__ W1b,
    const float* __restrict__ g1, const float* __restrict__ b1,
    const ushort_t* __restrict__ catB, const ushort_t* __restrict__ Wfb,
    const float* __restrict__ g_fc, const float* __restrict__ b_fc,
    float* __restrict__ out, int ntiles)
{
    __shared__ __align__(16) short h0sA[32 * 128], h0sB[32 * 128];   // 2×8 KB, swizzled; reused for h-norm
    __shared__ __align__(16) short msgA[32 * 128], msgB[32 * 128];   // 2×8 KB, swizzled
    __shared__ float b0s[128];
    __shared__ float2 partA[8][32], partB[8][32];
    __shared__ float gA[128], bA[128], gC[128], bC[128];

    const int t = threadIdx.x;
    const int w = t >> 6;                            // 8 waves
    const int l = t & 63;
    const int l15 = l & 15, lg = l >> 4;

    if (t < 128) {
        gA[t] = g1[t];   bA[t] = b1[t];
        gC[t] = g_fc[t]; bC[t] = b_fc[t];
        b0s[t] = b0[t];
    }

    const bh8 bzero = {0, 0, 0, 0, 0, 0, 0, 0};
    // weight fragments (bf16) in registers: 16 cols/wave
    bh8 w0f, w1b[4], wfb[8];
    {
        const int wr = 16 * w + l15;                 // weight row = output col
        w0f = (lg == 0) ? *(const bh8*)(W0b + wr * 8) : bzero;   // K=8 in lg==0 lanes
#pragma unroll
        for (int s = 0; s < 4; ++s)
            w1b[s] = *(const bh8*)(W1b + (size_t)wr * 128 + s * 32 + lg * 8);
#pragma unroll
        for (int s = 0; s < 8; ++s)
            wfb[s] = *(const bh8*)(Wfb + (size_t)wr * 256 + s * 32 + lg * 8);
    }
    __syncthreads();

    const f4v fzero = {0.f, 0.f, 0.f, 0.f};
    const int stride = (int)gridDim.x;
    const int npairs = (ntiles + 1) >> 1;

    for (int j = blockIdx.x; j < npairs; j += stride) {
        const int tileA = 2 * j, tileB = 2 * j + 1;
        const bool hasB = (tileB < ntiles);
        const int rowA0 = tileA * 32, rowB0 = tileB * 32;

        // ===== phase 0: GEMM1 via MFMA (A,B) -> h0sX + catB msg copy (A,B) -> msgX =====
        {
            bh8 xfA[2], xfB[2];
            xfA[0] = bzero; xfA[1] = bzero; xfB[0] = bzero; xfB[1] = bzero;
            if (lg == 0) {
#pragma unroll
                for (int m = 0; m < 2; ++m) {
                    const int row = 16 * m + l15;
                    float vv[8];
                    const float* p = mapx + (size_t)(rowA0 + row) * 8;
                    *(float4*)&vv[0] = *(const float4*)p;
                    *(float4*)&vv[4] = *(const float4*)(p + 4);
                    union { unsigned short s[8]; bh8 b; } ua;
#pragma unroll
                    for (int q2 = 0; q2 < 8; ++q2) ua.s[q2] = f2bf(vv[q2]);
                    xfA[m] = ua.b;
                    if (hasB) {
                        const float* pb2 = mapx + (size_t)(rowB0 + row) * 8;
                        *(float4*)&vv[0] = *(const float4*)pb2;
                        *(float4*)&vv[4] = *(const float4*)(pb2 + 4);
                        union { unsigned short s[8]; bh8 b; } ub;
#pragma unroll
                        for (int q2 = 0; q2 < 8; ++q2) ub.s[q2] = f2bf(vv[q2]);
                        xfB[m] = ub.b;
                    }
                }
            }
#pragma unroll
            for (int m = 0; m < 2; ++m) {
                f4v hA = __builtin_amdgcn_mfma_f32_16x16x32_bf16(w0f, xfA[m], fzero, 0, 0, 0);
                f4v hB = __builtin_amdgcn_mfma_f32_16x16x32_bf16(w0f, xfB[m], fzero, 0, 0, 0);
                const int row = 16 * m + l15;
                const int c00 = 16 * w + 4 * lg;
                const int ad = (row * 256 + c00 * 2) ^ ((row & 7) << 4);
                union { unsigned short s[4]; uint2 q2; } oA, oB;
#pragma unroll
                for (int reg = 0; reg < 4; ++reg) {
                    oA.s[reg] = f2bf(fmaxf(hA[reg] + b0s[c00 + reg], 0.f));
                    oB.s[reg] = f2bf(fmaxf(hB[reg] + b0s[c00 + reg], 0.f));
                }
                *(uint2*)((char*)h0sA + ad) = oA.q2;
                if (hasB) *(uint2*)((char*)h0sB + ad) = oB.q2;
            }
        }
        {
            const int r2 = t >> 4, cb = (t & 15) * 16;   // 16 B per thread
            const int ad = (r2 * 256 + cb) ^ ((r2 & 7) << 4);
            uint4 qa = *(const uint4*)((const char*)(catB + (size_t)(rowA0 + r2) * 128) + cb);
            *(uint4*)((char*)msgA + ad) = qa;
            if (hasB) {
                uint4 qb = *(const uint4*)((const char*)(catB + (size_t)(rowB0 + r2) * 128) + cb);
                *(uint4*)((char*)msgB + ad) = qb;
            }
        }
        __syncthreads();                              // bar1: h0s + msg ready

        // ===== GEMM2 (A then B) =====
        __builtin_amdgcn_s_setprio(1);
        f4v a2A[2], a2B[2];
        a2A[0] = fzero; a2A[1] = fzero; a2B[0] = fzero; a2B[1] = fzero;
#pragma unroll
        for (int s = 0; s < 4; ++s) {
            bh8 afA[2], afB[2];
#pragma unroll
            for (int m = 0; m < 2; ++m) {
                const int row = 16 * m + l15;
                const int a = (row * 256 + s * 64 + lg * 16) ^ ((row & 7) << 4);
                afA[m] = *(const bh8*)((const char*)h0sA + a);
                afB[m] = *(const bh8*)((const char*)h0sB + a);
            }
#pragma unroll
            for (int m = 0; m < 2; ++m) {
                a2A[m] = __builtin_amdgcn_mfma_f32_16x16x32_bf16(w1b[s], afA[m], a2A[m], 0, 0, 0);
                a2B[m] = __builtin_amdgcn_mfma_f32_16x16x32_bf16(w1b[s], afB[m], a2B[m], 0, 0, 0);
            }
        }
        __builtin_amdgcn_s_setprio(0);

        // GN1 partials (A and B)
#pragma unroll
        for (int m = 0; m < 2; ++m) {
            float aA = a2A[m][0] + a2A[m][1] + a2A[m][2] + a2A[m][3];
            float qA = a2A[m][0] * a2A[m][0] + a2A[m][1] * a2A[m][1] +
                       a2A[m][2] * a2A[m][2] + a2A[m][3] * a2A[m][3];
            float aB = a2B[m][0] + a2B[m][1] + a2B[m][2] + a2B[m][3];
            float qB = a2B[m][0] * a2B[m][0] + a2B[m][1] * a2B[m][1] +
                       a2B[m][2] * a2B[m][2] + a2B[m][3] * a2B[m][3];
            aA += __shfl_xor(aA, 16, 64); qA += __shfl_xor(qA, 16, 64);
            aA += __shfl_xor(aA, 32, 64); qA += __shfl_xor(qA, 32, 64);
            aB += __shfl_xor(aB, 16, 64); qB += __shfl_xor(qB, 16, 64);
            aB += __shfl_xor(aB, 32, 64); qB += __shfl_xor(qB, 32, 64);
            if (lg == 0) {
                partA[w][16 * m + l15] = make_float2(aA, qA);
                partB[w][16 * m + l15] = make_float2(aB, qB);
            }
        }
        __syncthreads();                              // bar2: partials ready; h0 data now dead

        // ===== stats + normalized-h -> h0sX (buffer reuse) =====
#pragma unroll
        for (int m = 0; m < 2; ++m) {
            const int row = 16 * m + l15;
            const int c00 = 16 * w + 4 * lg;
            const int ad = (row * 256 + c00 * 2) ^ ((row & 7) << 4);
            {
                float a = 0.f, q = 0.f;
#pragma unroll
                for (int pw = 0; pw < 8; ++pw) {
                    float2 pq = partA[pw][row];
                    a += pq.x; q += pq.y;
                }
                const float mean = a * (1.f / 128.f);
                const float var = q * (1.f / 128.f) - mean * mean;
                const float inv = rsqrtf(var + EPS);
                union { unsigned short s[4]; uint2 q2; } o;
#pragma unroll
                for (int reg = 0; reg < 4; ++reg) {
                    float v2 = (a2A[m][reg] - mean) * inv * gA[c00 + reg] + bA[c00 + reg];
                    o.s[reg] = f2bf(fmaxf(v2, 0.f));
                }
                *(uint2*)((char*)h0sA + ad) = o.q2;
            }
            {
                float a = 0.f, q = 0.f;
#pragma unroll
                for (int pw = 0; pw < 8; ++pw) {
                    float2 pq = partB[pw][row];
                    a += pq.x; q += pq.y;
                }
                const float mean = a * (1.f / 128.f);
                const float var = q * (1.f / 128.f) - mean * mean;
                const float inv = rsqrtf(var + EPS);
                union { unsigned short s[4]; uint2 q2; } o;
#pragma unroll
                for (int reg = 0; reg < 4; ++reg) {
                    float v2 = (a2B[m][reg] - mean) * inv * gA[c00 + reg] + bA[c00 + reg];
                    o.s[reg] = f2bf(fmaxf(v2, 0.f));
                }
                *(uint2*)((char*)h0sB + ad) = o.q2;
            }
        }
        __syncthreads();                              // bar3: h-norm + msg ready for GEMM3

        // ===== GEMM3 (A then B): h-half from h0sX, msg-half from msgX =====
        __builtin_amdgcn_s_setprio(1);
        f4v a3A[2], a3B[2];
        a3A[0] = fzero; a3A[1] = fzero; a3B[0] = fzero; a3B[1] = fzero;
#pragma unroll
        for (int s = 0; s < 4; ++s) {                 // k in [0,128): h-half
            bh8 afA[2], afB[2];
#pragma unroll
            for (int m = 0; m < 2; ++m) {
                const int row = 16 * m + l15;
                const int a = (row * 256 + s * 64 + lg * 16) ^ ((row & 7) << 4);
                afA[m] = *(const bh8*)((const char*)h0sA + a);
                afB[m] = *(const bh8*)((const char*)h0sB + a);
            }
#pragma unroll
            for (int m = 0; m < 2; ++m) {
                a3A[m] = __builtin_amdgcn_mfma_f32_16x16x32_bf16(wfb[s], afA[m], a3A[m], 0, 0, 0);
                a3B[m] = __builtin_amdgcn_mfma_f32_16x16x32_bf16(wfb[s], afB[m], a3B[m], 0, 0, 0);
            }
        }
#pragma unroll
        for (int s = 0; s < 4; ++s) {                 // k in [128,256): msg-half
            bh8 afA[2], afB[2];
#pragma unroll
            for (int m = 0; m < 2; ++m) {
                const int row = 16 * m + l15;
                const int a = (row * 256 + s * 64 + lg * 16) ^ ((row & 7) << 4);
                afA[m] = *(const bh8*)((const char*)msgA + a);
                afB[m] = *(const bh8*)((const char*)msgB + a);
            }
#pragma unroll
            for (int m = 0; m < 2; ++m) {
                a3A[m] = __builtin_amdgcn_mfma_f32_16x16x32_bf16(wfb[4 + s], afA[m], a3A[m], 0, 0, 0);
                a3B[m] = __builtin_amdgcn_mfma_f32_16x16x32_bf16(wfb[4 + s], afB[m], a3B[m], 0, 0, 0);
            }
        }
        __builtin_amdgcn_s_setprio(0);

        // GN-fc partials (A and B)
#pragma unroll
        for (int m = 0; m < 2; ++m) {
            float aA = a3A[m][0] + a3A[m][1] + a3A[m][2] + a3A[m][3];
            float qA = a3A[m][0] * a3A[m][0] + a3A[m][1] * a3A[m][1] +
                       a3A[m][2] * a3A[m][2] + a3A[m][3] * a3A[m][3];
            float aB = a3B[m][0] + a3B[m][1] + a3B[m][2] + a3B[m][3];
            float qB = a3B[m][0] * a3B[m][0] + a3B[m][1] * a3B[m][1] +
                       a3B[m][2] * a3B[m][2] + a3B[m][3] * a3B[m][3];
            aA += __shfl_xor(aA, 16, 64); qA += __shfl_xor(qA, 16, 64);
            aA += __shfl_xor(aA, 32, 64); qA += __shfl_xor(qA, 32, 64);
            aB += __shfl_xor(aB, 16, 64); qB += __shfl_xor(qB, 16, 64);
            aB += __shfl_xor(aB, 32, 64); qB += __shfl_xor(qB, 32, 64);
            if (lg == 0) {
                partA[w][16 * m + l15] = make_float2(aA, qA);
                partB[w][16 * m + l15] = make_float2(aB, qB);
            }
        }
        __syncthreads();                              // bar4: partials ready

        // ===== epilogue (A and B): stats, GN+ReLU, float4 store =====
#pragma unroll
        for (int m = 0; m < 2; ++m) {
            const int row = 16 * m + l15;
            const int c00 = 16 * w + 4 * lg;
            {
                float a = 0.f, q = 0.f;
#pragma unroll
                for (int pw = 0; pw < 8; ++pw) {
                    float2 pq = partA[pw][row];
                    a += pq.x; q += pq.y;
                }
                const float mean = a * (1.f / 128.f);
                const float var = q * (1.f / 128.f) - mean * mean;
                const float inv = rsqrtf(var + EPS);
                float4 o;
                o.x = fmaxf((a3A[m][0] - mean) * inv * gC[c00 + 0] + bC[c00 + 0], 0.f);
                o.y = fmaxf((a3A[m][1] - mean) * inv * gC[c00 + 1] + bC[c00 + 1], 0.f);
                o.z = fmaxf((a3A[m][2] - mean) * inv * gC[c00 + 2] + bC[c00 + 2], 0.f);
                o.w = fmaxf((a3A[m][3] - mean) * inv * gC[c00 + 3] + bC[c00 + 3], 0.f);
                *(float4*)&out[(size_t)(rowA0 + row) * 128 + c00] = o;
            }
            if (hasB) {
                float a = 0.f, q = 0.f;
#pragma unroll
                for (int pw = 0; pw < 8; ++pw) {
                    float2 pq = partB[pw][row];
                    a += pq.x; q += pq.y;
                }
                const float mean = a * (1.f / 128.f);
                const float var = q * (1.f / 128.f) - mean * mean;
                const float inv = rsqrtf(var + EPS);
                float4 o;
                o.x = fmaxf((a3B[m][0] - mean) * inv * gC[c00 + 0] + bC[c00 + 0], 0.f);
                o.y = fmaxf((a3B[m][1] - mean) * inv * gC[c00 + 1] + bC[c00 + 1], 0.f);
                o.z = fmaxf((a3B[m][2] - mean) * inv * gC[c00 + 2] + bC[c00 + 2], 0.f);
                o.w = fmaxf((a3B[m][3] - mean) * inv * gC[c00 + 3] + bC[c00 + 3], 0.f);
                *(float4*)&out[(size_t)(rowB0 + row) * 128 + c00] = o;
            }
        }
        // no trailing barrier:
        //   next-P0 h0sX/msgX writes vs this-P3 reads: separated by bar4.
        //   part rewrites gated by next bar1/bar2 chain (proven r6-r15).
    }
}

extern "C" void kernel_launch(void* const* d_in, const int* in_sizes, int n_in,
                              void* d_out, int out_size, void* d_ws, size_t ws_size,
                              hipStream_t stream) {
    const float* mapx = (const float*)d_in[0];
    const float* agt  = (const float*)d_in[1];
    const int*   u    = (const int*)d_in[2];
    const int*   v    = (const int*)d_in[3];
    const float* W0   = (const float*)d_in[4];
    const float* b0   = (const float*)d_in[5];
    const float* W1   = (const float*)d_in[6];
    const float* g1   = (const float*)d_in[7];
    const float* b1   = (const float*)d_in[8];
    const float* Wa   = (const float*)d_in[9];
    const float* g_bn = (const float*)d_in[10];
    const float* b_bn = (const float*)d_in[11];
    const float* Wf   = (const float*)d_in[12];
    const float* g_fc = (const float*)d_in[13];
    const float* b_fc = (const float*)d_in[14];
    int N = in_sizes[0] / 8;      // 500000
    int A = in_sizes[1] / 80;     // 20000
    int E = in_sizes[2];          // 500000
    float* out = (float*)d_out;

    char* ws = (char*)d_ws;
    unsigned short* Pb  = (unsigned short*)(ws + 0);
    ushort_t* W1b       = (ushort_t*)(ws + 5160960);
    ushort_t* Wfb       = (ushort_t*)(ws + 5193728);
    ushort_t* W0b       = (ushort_t*)(ws + 5259264);
    int*      cnt       = (int*)(ws + 5261312);
    int*      rp        = (int*)(ws + 9259264);
    int*      partials  = (int*)(ws + 11259392);
    int*      colv      = (int*)(ws + 11261440);
    ushort_t* catB      = (ushort_t*)(ws + 16777216);

    const int nb_scan = (N + 4095) / 4096;           // 123
    const int nb_e = (E + 255) / 256;                // 1954
    const int nb_proj = A / 32;                      // 625

    prep<<<512, 256, 0, stream>>>(W1, Wf, W0, W1b, Wfb, W0b, cnt, N);
    proj_hist<<<nb_proj + nb_e, 256, 0, stream>>>(agt, Wa, Pb, v, cnt, E, nb_proj);
    scan1<<<nb_scan, 256, 0, stream>>>(cnt, rp, partials, N);
    scan3<<<(N + 255) / 256, 256, 0, stream>>>(rp, partials, N, E, nb_scan);
    fill_csr<<<nb_e, 256, 0, stream>>>(u, v, rp, cnt, colv, E);
    gather_gn<<<N / 32, 256, 0, stream>>>(Pb, rp, colv, g_bn, b_bn, catB);

    int ntiles = N / 32;          // 15625 exact
    fused<<<768, 512, 0, stream>>>(mapx, W0b, b0, W1b, g1, b1, catB,
                                   Wfb, g_fc, b_fc, out, ntiles);
}

// Round 17
// 309.814 us; speedup vs baseline: 1.0422x; 1.0422x over previous
//
#include <hip/hip_runtime.h>
#include <stdint.h>

#define EPS 1e-5f

typedef short bh8 __attribute__((ext_vector_type(8)));   // 8 bf16 in 4 VGPRs
typedef float f4v __attribute__((ext_vector_type(4)));   // MFMA accumulator
typedef unsigned short ushort_t;

static __device__ __forceinline__ unsigned short f2bf(float f) {
    unsigned u = __builtin_bit_cast(unsigned, f);
    u += 0x7fffu + ((u >> 16) & 1u);          // RNE
    return (unsigned short)(u >> 16);
}

static __device__ __forceinline__ float bfbits(unsigned x) {
    return __builtin_bit_cast(float, x);
}

// accumulate 16 bf16 channels (2×uint4) into tv
static __device__ __forceinline__ void acc16(float* tv, uint4 qa, uint4 qb) {
    unsigned wd[8] = {qa.x, qa.y, qa.z, qa.w, qb.x, qb.y, qb.z, qb.w};
#pragma unroll
    for (int p = 0; p < 8; ++p) {
        tv[2 * p + 0] += bfbits(wd[p] << 16);
        tv[2 * p + 1] += bfbits(wd[p] & 0xffff0000u);
    }
}

// ---------------- ws layout (bytes) ----------------
// Pb   (bf16): 0          size 5,120,000
// W1b  (bf16): 5,160,960  size 32,768
// Wfb  (bf16): 5,193,728  size 65,536
// W0b  (bf16): 5,259,264  size 2,048
// cnt  (int) : 5,261,312  size 2,000,000   (zeroed by prep; fill_csr restores to 0)
// rp   (int) : 9,259,264  size 2,000,004
// partials   : 11,259,392 size 492
// col  (int) : 11,261,440 size 2,000,000
// catB (bf16): 16,777,216 size 128,000,000

// prep: bf16-convert W1/Wf/W0, zero cnt
__global__ __launch_bounds__(256) void prep(const float* __restrict__ W1,
                                            const float* __restrict__ Wf,
                                            const float* __restrict__ W0,
                                            ushort_t* __restrict__ W1b,
                                            ushort_t* __restrict__ Wfb,
                                            ushort_t* __restrict__ W0b,
                                            int* __restrict__ cnt, int n) {
    int i = blockIdx.x * 256 + threadIdx.x;
    if (i < 16384) W1b[i] = f2bf(W1[i]);
    else if (i < 49152) { int j = i - 16384; Wfb[j] = f2bf(Wf[j]); }
    else if (i < 50176) { int j = i - 49152; W0b[j] = f2bf(W0[j]); }
    for (int k = i; k < n; k += gridDim.x * 256) cnt[k] = 0;
}

// ---------------- merged: P = agt_x @ Wa^T  (blocks < nbProj)  +  hist_v (rest) ----------
__global__ __launch_bounds__(256) void proj_hist(const float* __restrict__ agt,
                                                 const float* __restrict__ Wa,
                                                 unsigned short* __restrict__ Pb,
                                                 const int* __restrict__ v,
                                                 int* __restrict__ cnt,
                                                 int E, int nbProj) {
    __shared__ float WT[80 * 128];   // WT[k*128+c] = Wa[c*80+k]
    __shared__ float xT[80][32];
    int t = threadIdx.x;
    if ((int)blockIdx.x >= nbProj) {   // histogram branch (no LDS use)
        int e = ((int)blockIdx.x - nbProj) * 256 + t;
        if (e < E) atomicAdd(&cnt[v[e]], 1);
        return;
    }
    int row0 = blockIdx.x * 32;
#pragma unroll
    for (int m = 0; m < 40; ++m) {
        int f = t + 256 * m;
        int k = f >> 7, c = f & 127;
        WT[f] = Wa[c * 80 + k];
    }
#pragma unroll
    for (int m = 0; m < 10; ++m) {
        int f = t + 256 * m;
        int r = f / 80, k = f - r * 80;
        xT[k][r] = agt[(size_t)(row0 + r) * 80 + k];
    }
    __syncthreads();
    int tx = t & 31, ty = t >> 5;
    float acc[4][4] = {};
    for (int k = 0; k < 80; ++k) {
        float4 xv = *(const float4*)&xT[k][ty * 4];
        float4 wv = *(const float4*)&WT[k * 128 + tx * 4];
        float xa[4] = {xv.x, xv.y, xv.z, xv.w};
        float wa[4] = {wv.x, wv.y, wv.z, wv.w};
#pragma unroll
        for (int i = 0; i < 4; ++i)
#pragma unroll
            for (int j = 0; j < 4; ++j) acc[i][j] = fmaf(xa[i], wa[j], acc[i][j]);
    }
#pragma unroll
    for (int i = 0; i < 4; ++i) {
        int r = row0 + ty * 4 + i;
        union { unsigned short s[4]; uint2 q; } o;
#pragma unroll
        for (int j = 0; j < 4; ++j) o.s[j] = f2bf(acc[i][j]);
        *(uint2*)&Pb[(size_t)r * 128 + tx * 4] = o.q;
    }
}

__global__ __launch_bounds__(256) void scan1(const int* __restrict__ cnt,
                                             int* __restrict__ rp,
                                             int* __restrict__ partials, int n) {
    __shared__ int lds[256];
    int b = blockIdx.x, t = threadIdx.x;
    int base = b * 4096 + t * 16;
    int vv[16];
    int run = 0;
#pragma unroll
    for (int i = 0; i < 16; ++i) {
        int c = (base + i < n) ? cnt[base + i] : 0;
        vv[i] = run;
        run += c;
    }
    lds[t] = run;
    __syncthreads();
#pragma unroll
    for (int off = 1; off < 256; off <<= 1) {
        int x = (t >= off) ? lds[t - off] : 0;
        __syncthreads();
        lds[t] += x;
        __syncthreads();
    }
    int excl = lds[t] - run;
    if (t == 255) partials[b] = lds[255];
#pragma unroll
    for (int i = 0; i < 16; ++i)
        if (base + i < n) rp[base + i] = excl + vv[i];
}

// scan3 with scan2 folded in
__global__ __launch_bounds__(256) void scan3(int* __restrict__ rp,
                                             const int* __restrict__ partials,
                                             int n, int E, int nb) {
    __shared__ int pref;
    int i = blockIdx.x * 256 + threadIdx.x;
    int chunk = (blockIdx.x * 256) >> 12;
    if (threadIdx.x == 0) {
        int s = 0;
        for (int b = 0; b < chunk; ++b) s += partials[b];
        pref = s;
    }
    __syncthreads();
    if (i < n) rp[i] += pref;
    if (i == 0) rp[n] = E;
}

// slot allocation via atomicSub on cnt (leaves cnt at 0 afterwards)
__global__ void fill_csr(const int* __restrict__ u, const int* __restrict__ v,
                         const int* __restrict__ rp, int* __restrict__ cnt,
                         int* __restrict__ col, int E) {
    int e = blockIdx.x * 256 + threadIdx.x;
    if (e < E) {
        int vv = v[e];
        int pos = rp[vv] + (atomicSub(&cnt[vv], 1) - 1);
        col[pos] = u[e];
    }
}

// ---------------- gather + GN_bn + ReLU + bf16 pack -> catB[N][128] ----------------
__global__ __launch_bounds__(256) void gather_gn(
    const unsigned short* __restrict__ Pb, const int* __restrict__ rp,
    const int* __restrict__ col, const float* __restrict__ g_bn,
    const float* __restrict__ b_bn, ushort_t* __restrict__ catB) {
    const int t = threadIdx.x;
    const int node = blockIdx.x * 32 + (t >> 3);
    const int c0 = (t & 7) * 16;
    const int beg = rp[node];
    const int deg = rp[node + 1] - beg;
    const int ca = col[(deg > 0) ? beg : 0];
    const int cb = col[(deg > 1) ? beg + 1 : 0];
    const int cc = col[(deg > 2) ? beg + 2 : 0];
    const int cd = col[(deg > 3) ? beg + 3 : 0];
    const unsigned short* pB = Pb + c0;
    float tv[16] = {};
    if (deg > 0) { const uint4* p = (const uint4*)(pB + (size_t)ca * 128); acc16(tv, p[0], p[1]); }
    if (deg > 1) { const uint4* p = (const uint4*)(pB + (size_t)cb * 128); acc16(tv, p[0], p[1]); }
    if (deg > 2) { const uint4* p = (const uint4*)(pB + (size_t)cc * 128); acc16(tv, p[0], p[1]); }
    if (deg > 3) { const uint4* p = (const uint4*)(pB + (size_t)cd * 128); acc16(tv, p[0], p[1]); }
    for (int k = 4; k < deg; ++k) {
        const uint4* p = (const uint4*)(pB + (size_t)col[beg + k] * 128);
        acc16(tv, p[0], p[1]);
    }
    float a = 0.f, q = 0.f;
#pragma unroll
    for (int i = 0; i < 16; ++i) { a += tv[i]; q += tv[i] * tv[i]; }
#pragma unroll
    for (int msk = 1; msk < 8; msk <<= 1) {
        a += __shfl_xor(a, msk, 64);
        q += __shfl_xor(q, msk, 64);
    }
    const float mean = a * (1.f / 128.f);
    const float var = q * (1.f / 128.f) - mean * mean;
    const float inv = rsqrtf(var + EPS);
    union { unsigned short s[16]; uint4 q4[2]; } o;
#pragma unroll
    for (int i = 0; i < 16; ++i) {
        const int cch = c0 + i;
        o.s[i] = f2bf(fmaxf((tv[i] - mean) * inv * g_bn[cch] + b_bn[cch], 0.f));
    }
    uint4* dst = (uint4*)(catB + (size_t)node * 128 + c0);
    dst[0] = o.q4[0];
    dst[1] = o.q4[1];
}

// ---------------- fused kernel: r15 configuration (no setprio) ----------------
// 512 threads, 8 waves; wave w owns output cols [16w,16w+16) for BOTH tiles A/B.
// GEMM1 (K=8) zero-padded to K=32 MFMA. h0sX reused for normalized-h. 4 barriers/pair.
__global__ __launch_bounds__(512, 4) void fused(
    const float* __restrict__ mapx, const ushort_t* __restrict__ W0b,
    const float* __restrict__ b0, const ushort_t* __restrict__ W1b,
    const float* __restrict__ g1, const float* __restrict__ b1,
    const ushort_t* __restrict__ catB, const ushort_t* __restrict__ Wfb,
    const float* __restrict__ g_fc, const float* __restrict__ b_fc,
    float* __restrict__ out, int ntiles)
{
    __shared__ __align__(16) short h0sA[32 * 128], h0sB[32 * 128];   // 2×8 KB, swizzled; reused for h-norm
    __shared__ __align__(16) short msgA[32 * 128], msgB[32 * 128];   // 2×8 KB, swizzled
    __shared__ float b0s[128];
    __shared__ float2 partA[8][32], partB[8][32];
    __shared__ float gA[128], bA[128], gC[128], bC[128];

    const int t = threadIdx.x;
    const int w = t >> 6;                            // 8 waves
    const int l = t & 63;
    const int l15 = l & 15, lg = l >> 4;

    if (t < 128) {
        gA[t] = g1[t];   bA[t] = b1[t];
        gC[t] = g_fc[t]; bC[t] = b_fc[t];
        b0s[t] = b0[t];
    }

    const bh8 bzero = {0, 0, 0, 0, 0, 0, 0, 0};
    // weight fragments (bf16) in registers: 16 cols/wave
    bh8 w0f, w1b[4], wfb[8];
    {
        const int wr = 16 * w + l15;                 // weight row = output col
        w0f = (lg == 0) ? *(const bh8*)(W0b + wr * 8) : bzero;   // K=8 in lg==0 lanes
#pragma unroll
        for (int s = 0; s < 4; ++s)
            w1b[s] = *(const bh8*)(W1b + (size_t)wr * 128 + s * 32 + lg * 8);
#pragma unroll
        for (int s = 0; s < 8; ++s)
            wfb[s] = *(const bh8*)(Wfb + (size_t)wr * 256 + s * 32 + lg * 8);
    }
    __syncthreads();

    const f4v fzero = {0.f, 0.f, 0.f, 0.f};
    const int stride = (int)gridDim.x;
    const int npairs = (ntiles + 1) >> 1;

    for (int j = blockIdx.x; j < npairs; j += stride) {
        const int tileA = 2 * j, tileB = 2 * j + 1;
        const bool hasB = (tileB < ntiles);
        const int rowA0 = tileA * 32, rowB0 = tileB * 32;

        // ===== phase 0: GEMM1 via MFMA (A,B) -> h0sX + catB msg copy (A,B) -> msgX =====
        {
            bh8 xfA[2], xfB[2];
            xfA[0] = bzero; xfA[1] = bzero; xfB[0] = bzero; xfB[1] = bzero;
            if (lg == 0) {
#pragma unroll
                for (int m = 0; m < 2; ++m) {
                    const int row = 16 * m + l15;
                    float vv[8];
                    const float* p = mapx + (size_t)(rowA0 + row) * 8;
                    *(float4*)&vv[0] = *(const float4*)p;
                    *(float4*)&vv[4] = *(const float4*)(p + 4);
                    union { unsigned short s[8]; bh8 b; } ua;
#pragma unroll
                    for (int q2 = 0; q2 < 8; ++q2) ua.s[q2] = f2bf(vv[q2]);
                    xfA[m] = ua.b;
                    if (hasB) {
                        const float* pb2 = mapx + (size_t)(rowB0 + row) * 8;
                        *(float4*)&vv[0] = *(const float4*)pb2;
                        *(float4*)&vv[4] = *(const float4*)(pb2 + 4);
                        union { unsigned short s[8]; bh8 b; } ub;
#pragma unroll
                        for (int q2 = 0; q2 < 8; ++q2) ub.s[q2] = f2bf(vv[q2]);
                        xfB[m] = ub.b;
                    }
                }
            }
#pragma unroll
            for (int m = 0; m < 2; ++m) {
                f4v hA = __builtin_amdgcn_mfma_f32_16x16x32_bf16(w0f, xfA[m], fzero, 0, 0, 0);
                f4v hB = __builtin_amdgcn_mfma_f32_16x16x32_bf16(w0f, xfB[m], fzero, 0, 0, 0);
                const int row = 16 * m + l15;
                const int c00 = 16 * w + 4 * lg;
                const int ad = (row * 256 + c00 * 2) ^ ((row & 7) << 4);
                union { unsigned short s[4]; uint2 q2; } oA, oB;
#pragma unroll
                for (int reg = 0; reg < 4; ++reg) {
                    oA.s[reg] = f2bf(fmaxf(hA[reg] + b0s[c00 + reg], 0.f));
                    oB.s[reg] = f2bf(fmaxf(hB[reg] + b0s[c00 + reg], 0.f));
                }
                *(uint2*)((char*)h0sA + ad) = oA.q2;
                if (hasB) *(uint2*)((char*)h0sB + ad) = oB.q2;
            }
        }
        {
            const int r2 = t >> 4, cb = (t & 15) * 16;   // 16 B per thread
            const int ad = (r2 * 256 + cb) ^ ((r2 & 7) << 4);
            uint4 qa = *(const uint4*)((const char*)(catB + (size_t)(rowA0 + r2) * 128) + cb);
            *(uint4*)((char*)msgA + ad) = qa;
            if (hasB) {
                uint4 qb = *(const uint4*)((const char*)(catB + (size_t)(rowB0 + r2) * 128) + cb);
                *(uint4*)((char*)msgB + ad) = qb;
            }
        }
        __syncthreads();                              // bar1: h0s + msg ready

        // ===== GEMM2 (A then B) =====
        f4v a2A[2], a2B[2];
        a2A[0] = fzero; a2A[1] = fzero; a2B[0] = fzero; a2B[1] = fzero;
#pragma unroll
        for (int s = 0; s < 4; ++s) {
            bh8 afA[2], afB[2];
#pragma unroll
            for (int m = 0; m < 2; ++m) {
                const int row = 16 * m + l15;
                const int a = (row * 256 + s * 64 + lg * 16) ^ ((row & 7) << 4);
                afA[m] = *(const bh8*)((const char*)h0sA + a);
                afB[m] = *(const bh8*)((const char*)h0sB + a);
            }
#pragma unroll
            for (int m = 0; m < 2; ++m) {
                a2A[m] = __builtin_amdgcn_mfma_f32_16x16x32_bf16(w1b[s], afA[m], a2A[m], 0, 0, 0);
                a2B[m] = __builtin_amdgcn_mfma_f32_16x16x32_bf16(w1b[s], afB[m], a2B[m], 0, 0, 0);
            }
        }

        // GN1 partials (A and B)
#pragma unroll
        for (int m = 0; m < 2; ++m) {
            float aA = a2A[m][0] + a2A[m][1] + a2A[m][2] + a2A[m][3];
            float qA = a2A[m][0] * a2A[m][0] + a2A[m][1] * a2A[m][1] +
                       a2A[m][2] * a2A[m][2] + a2A[m][3] * a2A[m][3];
            float aB = a2B[m][0] + a2B[m][1] + a2B[m][2] + a2B[m][3];
            float qB = a2B[m][0] * a2B[m][0] + a2B[m][1] * a2B[m][1] +
                       a2B[m][2] * a2B[m][2] + a2B[m][3] * a2B[m][3];
            aA += __shfl_xor(aA, 16, 64); qA += __shfl_xor(qA, 16, 64);
            aA += __shfl_xor(aA, 32, 64); qA += __shfl_xor(qA, 32, 64);
            aB += __shfl_xor(aB, 16, 64); qB += __shfl_xor(qB, 16, 64);
            aB += __shfl_xor(aB, 32, 64); qB += __shfl_xor(qB, 32, 64);
            if (lg == 0) {
                partA[w][16 * m + l15] = make_float2(aA, qA);
                partB[w][16 * m + l15] = make_float2(aB, qB);
            }
        }
        __syncthreads();                              // bar2: partials ready; h0 data now dead

        // ===== stats + normalized-h -> h0sX (buffer reuse) =====
#pragma unroll
        for (int m = 0; m < 2; ++m) {
            const int row = 16 * m + l15;
            const int c00 = 16 * w + 4 * lg;
            const int ad = (row * 256 + c00 * 2) ^ ((row & 7) << 4);
            {
                float a = 0.f, q = 0.f;
#pragma unroll
                for (int pw = 0; pw < 8; ++pw) {
                    float2 pq = partA[pw][row];
                    a += pq.x; q += pq.y;
                }
                const float mean = a * (1.f / 128.f);
                const float var = q * (1.f / 128.f) - mean * mean;
                const float inv = rsqrtf(var + EPS);
                union { unsigned short s[4]; uint2 q2; } o;
#pragma unroll
                for (int reg = 0; reg < 4; ++reg) {
                    float v2 = (a2A[m][reg] - mean) * inv * gA[c00 + reg] + bA[c00 + reg];
                    o.s[reg] = f2bf(fmaxf(v2, 0.f));
                }
                *(uint2*)((char*)h0sA + ad) = o.q2;
            }
            {
                float a = 0.f, q = 0.f;
#pragma unroll
                for (int pw = 0; pw < 8; ++pw) {
                    float2 pq = partB[pw][row];
                    a += pq.x; q += pq.y;
                }
                const float mean = a * (1.f / 128.f);
                const float var = q * (1.f / 128.f) - mean * mean;
                const float inv = rsqrtf(var + EPS);
                union { unsigned short s[4]; uint2 q2; } o;
#pragma unroll
                for (int reg = 0; reg < 4; ++reg) {
                    float v2 = (a2B[m][reg] - mean) * inv * gA[c00 + reg] + bA[c00 + reg];
                    o.s[reg] = f2bf(fmaxf(v2, 0.f));
                }
                *(uint2*)((char*)h0sB + ad) = o.q2;
            }
        }
        __syncthreads();                              // bar3: h-norm + msg ready for GEMM3

        // ===== GEMM3 (A then B): h-half from h0sX, msg-half from msgX =====
        f4v a3A[2], a3B[2];
        a3A[0] = fzero; a3A[1] = fzero; a3B[0] = fzero; a3B[1] = fzero;
#pragma unroll
        for (int s = 0; s < 4; ++s) {                 // k in [0,128): h-half
            bh8 afA[2], afB[2];
#pragma unroll
            for (int m = 0; m < 2; ++m) {
                const int row = 16 * m + l15;
                const int a = (row * 256 + s * 64 + lg * 16) ^ ((row & 7) << 4);
                afA[m] = *(const bh8*)((const char*)h0sA + a);
                afB[m] = *(const bh8*)((const char*)h0sB + a);
            }
#pragma unroll
            for (int m = 0; m < 2; ++m) {
                a3A[m] = __builtin_amdgcn_mfma_f32_16x16x32_bf16(wfb[s], afA[m], a3A[m], 0, 0, 0);
                a3B[m] = __builtin_amdgcn_mfma_f32_16x16x32_bf16(wfb[s], afB[m], a3B[m], 0, 0, 0);
            }
        }
#pragma unroll
        for (int s = 0; s < 4; ++s) {                 // k in [128,256): msg-half
            bh8 afA[2], afB[2];
#pragma unroll
            for (int m = 0; m < 2; ++m) {
                const int row = 16 * m + l15;
                const int a = (row * 256 + s * 64 + lg * 16) ^ ((row & 7) << 4);
                afA[m] = *(const bh8*)((const char*)msgA + a);
                afB[m] = *(const bh8*)((const char*)msgB + a);
            }
#pragma unroll
            for (int m = 0; m < 2; ++m) {
                a3A[m] = __builtin_amdgcn_mfma_f32_16x16x32_bf16(wfb[4 + s], afA[m], a3A[m], 0, 0, 0);
                a3B[m] = __builtin_amdgcn_mfma_f32_16x16x32_bf16(wfb[4 + s], afB[m], a3B[m], 0, 0, 0);
            }
        }

        // GN-fc partials (A and B)
#pragma unroll
        for (int m = 0; m < 2; ++m) {
            float aA = a3A[m][0] + a3A[m][1] + a3A[m][2] + a3A[m][3];
            float qA = a3A[m][0] * a3A[m][0] + a3A[m][1] * a3A[m][1] +
                       a3A[m][2] * a3A[m][2] + a3A[m][3] * a3A[m][3];
            float aB = a3B[m][0] + a3B[m][1] + a3B[m][2] + a3B[m][3];
            float qB = a3B[m][0] * a3B[m][0] + a3B[m][1] * a3B[m][1] +
                       a3B[m][2] * a3B[m][2] + a3B[m][3] * a3B[m][3];
            aA += __shfl_xor(aA, 16, 64); qA += __shfl_xor(qA, 16, 64);
            aA += __shfl_xor(aA, 32, 64); qA += __shfl_xor(qA, 32, 64);
            aB += __shfl_xor(aB, 16, 64); qB += __shfl_xor(qB, 16, 64);
            aB += __shfl_xor(aB, 32, 64); qB += __shfl_xor(qB, 32, 64);
            if (lg == 0) {
                partA[w][16 * m + l15] = make_float2(aA, qA);
                partB[w][16 * m + l15] = make_float2(aB, qB);
            }
        }
        __syncthreads();                              // bar4: partials ready

        // ===== epilogue (A and B): stats, GN+ReLU, float4 store =====
#pragma unroll
        for (int m = 0; m < 2; ++m) {
            const int row = 16 * m + l15;
            const int c00 = 16 * w + 4 * lg;
            {
                float a = 0.f, q = 0.f;
#pragma unroll
                for (int pw = 0; pw < 8; ++pw) {
                    float2 pq = partA[pw][row];
                    a += pq.x; q += pq.y;
                }
                const float mean = a * (1.f / 128.f);
                const float var = q * (1.f / 128.f) - mean * mean;
                const float inv = rsqrtf(var + EPS);
                float4 o;
                o.x = fmaxf((a3A[m][0] - mean) * inv * gC[c00 + 0] + bC[c00 + 0], 0.f);
                o.y = fmaxf((a3A[m][1] - mean) * inv * gC[c00 + 1] + bC[c00 + 1], 0.f);
                o.z = fmaxf((a3A[m][2] - mean) * inv * gC[c00 + 2] + bC[c00 + 2], 0.f);
                o.w = fmaxf((a3A[m][3] - mean) * inv * gC[c00 + 3] + bC[c00 + 3], 0.f);
                *(float4*)&out[(size_t)(rowA0 + row) * 128 + c00] = o;
            }
            if (hasB) {
                float a = 0.f, q = 0.f;
#pragma unroll
                for (int pw = 0; pw < 8; ++pw) {
                    float2 pq = partB[pw][row];
                    a += pq.x; q += pq.y;
                }
                const float mean = a * (1.f / 128.f);
                const float var = q * (1.f / 128.f) - mean * mean;
                const float inv = rsqrtf(var + EPS);
                float4 o;
                o.x = fmaxf((a3B[m][0] - mean) * inv * gC[c00 + 0] + bC[c00 + 0], 0.f);
                o.y = fmaxf((a3B[m][1] - mean) * inv * gC[c00 + 1] + bC[c00 + 1], 0.f);
                o.z = fmaxf((a3B[m][2] - mean) * inv * gC[c00 + 2] + bC[c00 + 2], 0.f);
                o.w = fmaxf((a3B[m][3] - mean) * inv * gC[c00 + 3] + bC[c00 + 3], 0.f);
                *(float4*)&out[(size_t)(rowB0 + row) * 128 + c00] = o;
            }
        }
        // no trailing barrier:
        //   next-P0 h0sX/msgX writes vs this-P3 reads: separated by bar4.
        //   part rewrites gated by next bar1/bar2 chain (proven r6-r16).
    }
}

extern "C" void kernel_launch(void* const* d_in, const int* in_sizes, int n_in,
                              void* d_out, int out_size, void* d_ws, size_t ws_size,
                              hipStream_t stream) {
    const float* mapx = (const float*)d_in[0];
    const float* agt  = (const float*)d_in[1];
    const int*   u    = (const int*)d_in[2];
    const int*   v    = (const int*)d_in[3];
    const float* W0   = (const float*)d_in[4];
    const float* b0   = (const float*)d_in[5];
    const float* W1   = (const float*)d_in[6];
    const float* g1   = (const float*)d_in[7];
    const float* b1   = (const float*)d_in[8];
    const float* Wa   = (const float*)d_in[9];
    const float* g_bn = (const float*)d_in[10];
    const float* b_bn = (const float*)d_in[11];
    const float* Wf   = (const float*)d_in[12];
    const float* g_fc = (const float*)d_in[13];
    const float* b_fc = (const float*)d_in[14];
    int N = in_sizes[0] / 8;      // 500000
    int A = in_sizes[1] / 80;     // 20000
    int E = in_sizes[2];          // 500000
    float* out = (float*)d_out;

    char* ws = (char*)d_ws;
    unsigned short* Pb  = (unsigned short*)(ws + 0);
    ushort_t* W1b       = (ushort_t*)(ws + 5160960);
    ushort_t* Wfb       = (ushort_t*)(ws + 5193728);
    ushort_t* W0b       = (ushort_t*)(ws + 5259264);
    int*      cnt       = (int*)(ws + 5261312);
    int*      rp        = (int*)(ws + 9259264);
    int*      partials  = (int*)(ws + 11259392);
    int*      colv      = (int*)(ws + 11261440);
    ushort_t* catB      = (ushort_t*)(ws + 16777216);

    const int nb_scan = (N + 4095) / 4096;           // 123
    const int nb_e = (E + 255) / 256;                // 1954
    const int nb_proj = A / 32;                      // 625

    prep<<<512, 256, 0, stream>>>(W1, Wf, W0, W1b, Wfb, W0b, cnt, N);
    proj_hist<<<nb_proj + nb_e, 256, 0, stream>>>(agt, Wa, Pb, v, cnt, E, nb_proj);
    scan1<<<nb_scan, 256, 0, stream>>>(cnt, rp, partials, N);
    scan3<<<(N + 255) / 256, 256, 0, stream>>>(rp, partials, N, E, nb_scan);
    fill_csr<<<nb_e, 256, 0, stream>>>(u, v, rp, cnt, colv, E);
    gather_gn<<<N / 32, 256, 0, stream>>>(Pb, rp, colv, g_bn, b_bn, catB);

    int ntiles = N / 32;          // 15625 exact
    fused<<<768, 512, 0, stream>>>(mapx, W0b, b0, W1b, g1, b1, catB,
                                   Wfb, g_fc, b_fc, out, ntiles);
}